// Round 4
// baseline (288.415 us; speedup 1.0000x reference)
//
#include <hip/hip_runtime.h>
#include <math.h>

// DTW 2048x2048, single workgroup of 256 threads (4 waves).
// Thread = lane ln of wave wv owns 8 columns; row-blocks of BR=8 rows.
// Left-boundary exchange via __shfl_up (in-wave) and a ring mailbox in LDS
// across the 3 wave boundaries (one barrier per KK=8 iterations).
// The exchange + next-src prefetch are software-pipelined: issued at the
// BOTTOM of iteration n, consumed at n+1 (mailbox lag KK+1, DELTA=63+KK+1).

#define MM 2048
#define NN 2048
#define BR 8
#define BC 8
#define NT 256
#define NB (MM / BR)                 // 256 row-blocks
#define KK 8                         // barrier period (iterations)
#define DELTA (63 + KK + 1)          // 72: skew between adjacent waves
#define MAXSKEW (63 + 3 * DELTA)     // 279
#define NITER (NB + MAXSKEW)         // 535
#define NSP ((NITER + KK - 1) / KK)  // 67 superphases
#define RING (2 * KK)                // 16 mailbox slots per boundary
#define INFV 1e30f

__launch_bounds__(NT, 1)
__global__ void dtw_kernel(const float* __restrict__ src,
                           const float* __restrict__ tgt,
                           float* __restrict__ out)
{
    __shared__ float4 s_src4[MM / 4];       // 512 float4
    __shared__ float4 mbox[3][RING][2];     // 8 floats per slot

    const int tid  = threadIdx.x;
    const int wv   = tid >> 6;
    const int ln   = tid & 63;
    const int skew = ln + wv * DELTA;

    const float4* s4 = (const float4*)src;
    for (int i = tid; i < MM / 4; i += NT) s_src4[i] = s4[i];

    float tg[BC];
    #pragma unroll
    for (int k = 0; k < BC; ++k) tg[k] = tgt[tid * BC + k];

    // cur[] = bottom row of this thread's previous row-block (row-0 boundary = INF)
    float cur[BC];
    #pragma unroll
    for (int k = 0; k < BC; ++k) cur[k] = INFV;

    // corner = D[bi*BR][j0-1]; D[0][0]=0 for tid 0, else INF
    float corner = (tid == 0) ? 0.0f : INFV;

    // rcp = right column of my previous block (stays INFV while inactive)
    float rcp[BR];
    #pragma unroll
    for (int r = 0; r < BR; ++r) rcp[r] = INFV;

    __syncthreads();

    // ---- pipelined state for iteration 0 ----
    float lc[BR], psrow[BR];
    {
        #pragma unroll
        for (int r = 0; r < BR; ++r) lc[r] = INFV;  // shfl of INFV; wv>0 lane0 inactive
        int bin = 0 - skew; if (bin < 0) bin = 0;
        float4 a = s_src4[2 * bin], b = s_src4[2 * bin + 1];
        psrow[0] = a.x; psrow[1] = a.y; psrow[2] = a.z; psrow[3] = a.w;
        psrow[4] = b.x; psrow[5] = b.y; psrow[6] = b.z; psrow[7] = b.w;
    }

    for (int sp = 0; sp < NSP; ++sp) {
        #pragma unroll 1
        for (int it = 0; it < KK; ++it) {
            const int n  = sp * KK + it;
            const int bi = n - skew;

            if (0 <= bi && bi < NB) {
                float srow[BR], lcx[BR];
                #pragma unroll
                for (int r = 0; r < BR; ++r) { srow[r] = psrow[r]; lcx[r] = lc[r]; }

                float dg[BR], lv[BR];
                dg[0] = corner; lv[0] = lcx[0];
                #pragma unroll
                for (int r = 1; r < BR; ++r) { dg[r] = lcx[r - 1]; lv[r] = lcx[r]; }

                // anti-diagonal order inside the 8x8 block: 8 independent chains
                #pragma unroll
                for (int s = 0; s < BR + BC - 1; ++s) {
                    #pragma unroll
                    for (int r = 0; r < BR; ++r) {
                        const int k = s - r;
                        if (0 <= k && k < BC) {
                            float up = cur[k];
                            float m  = fminf(fminf(up, lv[r]), dg[r]);
                            float d  = srow[r] - tg[k];
                            float v  = fmaf(d, d, m);
                            dg[r] = up; lv[r] = v; cur[k] = v;
                        }
                    }
                }

                corner = lcx[BR - 1];
                #pragma unroll
                for (int r = 0; r < BR; ++r) rcp[r] = lv[r];
                if (ln == 63 && wv < 3) {
                    const int sl = n & (RING - 1);
                    mbox[wv][sl][0] = make_float4(rcp[0], rcp[1], rcp[2], rcp[3]);
                    mbox[wv][sl][1] = make_float4(rcp[4], rcp[5], rcp[6], rcp[7]);
                }
            }

            // ---- bottom: prepare iteration n+1 (unconditional; overlaps latency) ----
            {
                int bin = n + 1 - skew;
                if (bin < 0) bin = 0;
                if (bin > NB - 1) bin = NB - 1;
                float4 a = s_src4[2 * bin], b = s_src4[2 * bin + 1];
                psrow[0] = a.x; psrow[1] = a.y; psrow[2] = a.z; psrow[3] = a.w;
                psrow[4] = b.x; psrow[5] = b.y; psrow[6] = b.z; psrow[7] = b.w;

                #pragma unroll
                for (int r = 0; r < BR; ++r) lc[r] = __shfl_up(rcp[r], 1);
                if (ln == 0) {
                    if (wv == 0) {
                        #pragma unroll
                        for (int r = 0; r < BR; ++r) lc[r] = INFV;  // DP left edge
                    } else {
                        const int sl = (int)((unsigned)(n - KK) & (RING - 1));
                        float4 m0 = mbox[wv - 1][sl][0];
                        float4 m1 = mbox[wv - 1][sl][1];
                        lc[0] = m0.x; lc[1] = m0.y; lc[2] = m0.z; lc[3] = m0.w;
                        lc[4] = m1.x; lc[5] = m1.y; lc[6] = m1.z; lc[7] = m1.w;
                    }
                }
            }
        }
        __syncthreads();
    }

    // tid 255 computed block (NB-1, strip 255) at n = NITER-1; cur[7] = D[2048][2048]
    if (tid == NT - 1) out[0] = sqrtf(cur[BC - 1]);
}

extern "C" void kernel_launch(void* const* d_in, const int* in_sizes, int n_in,
                              void* d_out, int out_size, void* d_ws, size_t ws_size,
                              hipStream_t stream)
{
    (void)in_sizes; (void)n_in; (void)out_size; (void)d_ws; (void)ws_size;
    const float* source = (const float*)d_in[0];
    const float* target = (const float*)d_in[1];
    float* out = (float*)d_out;
    dtw_kernel<<<1, NT, 0, stream>>>(source, target, out);
}